// Round 6
// baseline (215.180 us; speedup 1.0000x reference)
//
#include <hip/hip_runtime.h>
#include <stdint.h>

#define S_ 2048
#define H_ 16

typedef short s16x8 __attribute__((ext_vector_type(8)));
typedef float f32x4 __attribute__((ext_vector_type(4)));
typedef float f32x16 __attribute__((ext_vector_type(16)));

__device__ __forceinline__ ushort f2bf(float f) {
    union { float f; uint32_t u; } v; v.f = f;
    uint32_t r = v.u + 0x7fffu + ((v.u >> 16) & 1u);
    return (ushort)(r >> 16);
}
__device__ __forceinline__ uint32_t cvtpk(float a, float b) {
    uint32_t r;
    asm("v_cvt_pk_bf16_f32 %0, %1, %2" : "=v"(r) : "v"(a), "v"(b));
    return r;
}
__device__ __forceinline__ void plswap(uint32_t& a, uint32_t& b) {
    auto r = __builtin_amdgcn_permlane32_swap((int)a, (int)b, false, false);
    a = (uint32_t)r[0];
    b = (uint32_t)r[1];
}
__device__ __forceinline__ float xmax32(float x) {
    uint32_t a = __float_as_uint(x), b = a;
    plswap(a, b);
    return fmaxf(__uint_as_float(a), __uint_as_float(b));
}
__device__ __forceinline__ float xadd32(float x) {
    uint32_t a = __float_as_uint(x), b = a;
    plswap(a, b);
    return __uint_as_float(a) + __uint_as_float(b);
}
__device__ __forceinline__ float exp2_fast(float x) {
    float r;
    asm("v_exp_f32 %0, %1" : "=v"(r) : "v"(x));
    return r;
}

// async global->LDS, 16B per lane. LDS dest = wave-uniform base + lane*16.
__device__ __forceinline__ void gld16(ushort* lds, const ushort* g) {
    auto* gp = reinterpret_cast<uint32_t __attribute__((address_space(1)))*>(
        reinterpret_cast<uintptr_t>(g));
    auto* lp = reinterpret_cast<uint32_t __attribute__((address_space(3)))*>(
        reinterpret_cast<uintptr_t>(lds));
    __builtin_amdgcn_global_load_lds(gp, lp, 16, 0, 0);
}

// ---- X fp32 -> bf16 ----
__global__ void cast_bf16(const float* __restrict__ src, ushort* __restrict__ dst) {
    size_t i = ((size_t)blockIdx.x * 256 + threadIdx.x) * 8;
    float4 x = *(const float4*)(src + i);
    float4 y = *(const float4*)(src + i + 4);
    s16x8 r;
    r[0] = (short)f2bf(x.x); r[1] = (short)f2bf(x.y);
    r[2] = (short)f2bf(x.z); r[3] = (short)f2bf(x.w);
    r[4] = (short)f2bf(y.x); r[5] = (short)f2bf(y.y);
    r[6] = (short)f2bf(y.z); r[7] = (short)f2bf(y.w);
    *(s16x8*)(dst + i) = r;
}

// ---- weight prep: dst[n*1024+k] = bf16(src[k*1024+n]) ----
__global__ void transpose_k4(const float* __restrict__ s0, const float* __restrict__ s1,
                             const float* __restrict__ s2, const float* __restrict__ s3,
                             ushort* __restrict__ d0, ushort* __restrict__ d1,
                             ushort* __restrict__ d2, ushort* __restrict__ d3) {
    const int z = blockIdx.z;
    const float* src = (z == 0) ? s0 : (z == 1) ? s1 : (z == 2) ? s2 : s3;
    ushort* dst      = (z == 0) ? d0 : (z == 1) ? d1 : (z == 2) ? d2 : d3;
    __shared__ ushort t[32][33];
    int bx = blockIdx.x * 32, by = blockIdx.y * 32;
    int x = threadIdx.x;
    for (int y = threadIdx.y; y < 32; y += 8)
        t[y][x] = f2bf(src[(size_t)(by + y) * 1024 + bx + x]);
    __syncthreads();
    for (int y = threadIdx.y; y < 32; y += 8)
        dst[(size_t)(bx + y) * 1024 + by + x] = t[x][y];
}

// ------------- 256x256 8-wave double-buffered GEMM (BK=64) ------------------
// C[m,n] = A[M,K] @ Bt[N,K]^T + bias. 512 threads = 8 waves (2M x 4N); each
// wave owns 128x64 output. LDS 128KB: 2 buffers x (A 256x64 + B 256x64) bf16.
// Per K-tile: issue next-tile staging (8 gld16) -> 4 MFMA phases (16 each)
// from LDS with raw s_barrier + setprio -> __syncthreads (drains vmcnt).
// Bank swizzle (T2, R5-proven both-sides pattern): LDS linear, SOURCE chunk
// XOR'd by row&7, ds_read applies the same XOR (row&7 == l16&7 for frags).
// mode 0: fp32 out[m*1024+n]
// mode 1: Q bf16 out[((b*16+h)*2048+s)*64+d] = v * 0.125*log2(e)
// mode 2: K bf16 same layout
// mode 3: Vt bf16 out[((b*16+h)*64+d)*2048+s] = v (4-pass LDS transpose)
#define MFMA16(a, b, c) __builtin_amdgcn_mfma_f32_16x16x32_bf16(a, b, c, 0, 0, 0)

__global__ __launch_bounds__(512, 2) void gemm256(
        const ushort* __restrict__ A,
        const ushort* __restrict__ Bt0, const ushort* __restrict__ Bt1,
        const ushort* __restrict__ Bt2,
        const float* __restrict__ bi0, const float* __restrict__ bi1,
        const float* __restrict__ bi2,
        void* __restrict__ o0, void* __restrict__ o1, void* __restrict__ o2,
        int mode0) {
    const int z = blockIdx.z;
    const ushort* Bt  = (z == 0) ? Bt0 : (z == 1) ? Bt1 : Bt2;
    const float* bia  = (z == 0) ? bi0 : (z == 1) ? bi1 : bi2;
    void* out         = (z == 0) ? o0  : (z == 1) ? o1  : o2;
    const int mode = mode0 + z;

    __shared__ __align__(16) ushort LB[2][2][16384];  // [buf][A/B][256*64] = 128KB

    const int t = threadIdx.x;
    const int lane = t & 63, w = t >> 6;
    const int wm = w >> 2, wn = w & 3;        // 2M x 4N wave grid
    const int quad = lane >> 4, l16 = lane & 15;
    const int m0 = blockIdx.y * 256, n0 = blockIdx.x * 256;
    const int K = 1024;
    const int NTK = K / 64;

    const f32x4 FZ = {0.f, 0.f, 0.f, 0.f};
    f32x4 acc[8][4];
#pragma unroll
    for (int i = 0; i < 8; i++)
#pragma unroll
        for (int j = 0; j < 4; j++) acc[i][j] = FZ;

    // staging: slot s = g*512 + t covers row g*64 + (t>>3), chunkpos t&7;
    // source chunk = (t&7) ^ (row&7)  (row&7 == (t>>3)&7 for all g)
    const int rr = t >> 3;
    const int ck = (((t & 7) ^ (rr & 7)) * 8);
    const ushort* sA0 = A  + (size_t)(m0 + rr) * K + ck;
    const ushort* sB0 = Bt + (size_t)(n0 + rr) * K + ck;
    const int wbase = w * 64 * 8;  // ushorts; HW adds lane*16B

#define STAGE(buf, kt) do {                                              \
    const int _o = (kt) * 64;                                            \
    gld16(&LB[buf][0][wbase],            sA0 + _o);                      \
    gld16(&LB[buf][0][wbase + 4096],     sA0 + (size_t)64  * K + _o);    \
    gld16(&LB[buf][0][wbase + 8192],     sA0 + (size_t)128 * K + _o);    \
    gld16(&LB[buf][0][wbase + 12288],    sA0 + (size_t)192 * K + _o);    \
    gld16(&LB[buf][1][wbase],            sB0 + _o);                      \
    gld16(&LB[buf][1][wbase + 4096],     sB0 + (size_t)64  * K + _o);    \
    gld16(&LB[buf][1][wbase + 8192],     sB0 + (size_t)128 * K + _o);    \
    gld16(&LB[buf][1][wbase + 12288],    sB0 + (size_t)192 * K + _o);    \
} while (0)

    // frag read swizzle: row&7 == l16&7
    const int fx = l16 & 7;
    const int ckA0 = ((0 + quad) ^ fx) * 8;   // ks=0
    const int ckA1 = ((4 + quad) ^ fx) * 8;   // ks=1
    const int aOff = (wm * 128 + l16) * 64;
    const int bOff = (wn * 64 + l16) * 64;

    STAGE(0, 0);
    __syncthreads();

    for (int kt = 0; kt < NTK; ++kt) {
        const int cur = kt & 1;
        if (kt + 1 < NTK) STAGE(cur ^ 1, kt + 1);
        const ushort* Ab = &LB[cur][0][0];
        const ushort* Bb = &LB[cur][1][0];

        s16x8 bf[4][2];
#pragma unroll
        for (int j = 0; j < 4; j++) {
            bf[j][0] = *(const s16x8*)&Bb[bOff + j * 1024 + ckA0];
            bf[j][1] = *(const s16x8*)&Bb[bOff + j * 1024 + ckA1];
        }
#pragma unroll
        for (int p = 0; p < 4; ++p) {
            s16x8 af[2][2];
#pragma unroll
            for (int i2 = 0; i2 < 2; i2++) {
                af[i2][0] = *(const s16x8*)&Ab[aOff + (p * 2 + i2) * 1024 + ckA0];
                af[i2][1] = *(const s16x8*)&Ab[aOff + (p * 2 + i2) * 1024 + ckA1];
            }
            __builtin_amdgcn_s_barrier();
            __builtin_amdgcn_s_setprio(1);
#pragma unroll
            for (int i2 = 0; i2 < 2; i2++)
#pragma unroll
                for (int j = 0; j < 4; j++) {
                    acc[p * 2 + i2][j] = MFMA16(af[i2][0], bf[j][0], acc[p * 2 + i2][j]);
                    acc[p * 2 + i2][j] = MFMA16(af[i2][1], bf[j][1], acc[p * 2 + i2][j]);
                }
            __builtin_amdgcn_s_setprio(0);
        }
        __syncthreads();  // drains vmcnt: next tile staged; safe to swap buffers
    }

    if (mode == 3) {
        // V^T epilogue: 4 passes of 64(n) x 256(m) LDS transpose, coalesced stores
        ushort* T = &LB[0][0][0];  // 32KB
        const int b_ = m0 >> 11, s_base = m0 & 2047;
        __syncthreads();
#pragma unroll
        for (int pass = 0; pass < 4; ++pass) {
            if (wn == pass) {
#pragma unroll
                for (int j = 0; j < 4; j++) {
                    int nl = j * 16 + l16;
                    float bv = bia[n0 + pass * 64 + nl];
#pragma unroll
                    for (int i = 0; i < 8; i++) {
#pragma unroll
                        for (int r = 0; r < 4; r++) {
                            int ml = wm * 128 + i * 16 + quad * 4 + r;
                            T[nl * 256 + (ml ^ ((nl & 15) << 3))] = f2bf(acc[i][j][r] + bv);
                        }
                    }
                }
            }
            __syncthreads();
            {
                int row = t >> 3, cb = (t & 7) * 4;
                int ng = n0 + pass * 64 + row;
                int h = ng >> 6, d = ng & 63;
                ushort* op = (ushort*)out + ((size_t)((b_ * 16 + h) * 64 + d)) * 2048
                             + s_base + (t & 7) * 32;
#pragma unroll
                for (int c = 0; c < 4; c++) {
                    int cc = (cb + c) ^ (row & 15);
                    *(s16x8*)(op + c * 8) = *(const s16x8*)&T[row * 256 + cc * 8];
                }
            }
            __syncthreads();
        }
        return;
    }

#pragma unroll
    for (int j = 0; j < 4; j++) {
        int n = n0 + wn * 64 + j * 16 + l16;
        float bv = bia[n];
#pragma unroll
        for (int i = 0; i < 8; i++) {
#pragma unroll
            for (int r = 0; r < 4; r++) {
                int m = m0 + wm * 128 + i * 16 + quad * 4 + r;
                float v = acc[i][j][r] + bv;
                if (mode == 0) {
                    ((float*)out)[(size_t)m * 1024 + n] = v;
                } else {
                    int b_ = m >> 11, s = m & 2047;
                    int h = n >> 6, d = n & 63;
                    if (mode == 1)  // 0.125*log2(e): attn softmax runs in exp2 domain
                        ((ushort*)out)[((size_t)(b_ * 16 + h) * 2048 + s) * 64 + d] = f2bf(v * 0.18033688011112042f);
                    else
                        ((ushort*)out)[((size_t)(b_ * 16 + h) * 2048 + s) * 64 + d] = f2bf(v);
                }
            }
        }
    }
#undef STAGE
}

// ---------------- MFMA flash attention: LDS-staged 2-phase pipeline ----------
// (R5 structure, verified: 60.2us.) Added T13 defer-max: skip O/l rescale when
// no lane's tile-max exceeds m_run+8 (exp2 domain; P bounded by 2^8, f32-safe).
#define MFMA32(a, b, c) __builtin_amdgcn_mfma_f32_32x32x16_bf16(a, b, c, 0, 0, 0)

__global__ __launch_bounds__(256, 2) void attn(const ushort* __restrict__ q_ws,
                                               const ushort* __restrict__ k_ws,
                                               const ushort* __restrict__ vt_ws,
                                               ushort* __restrict__ ctx) {
    __shared__ __align__(16) ushort Kb[2][4096];
    __shared__ __align__(16) ushort Vb[2][4096];
    __shared__ ushort obuf[4][32][72];

    const int t = threadIdx.x, lane = t & 63, w = t >> 6;
    const int l32 = lane & 31, hi = lane >> 5;

    const int bid = blockIdx.x;
    const int j_ = bid >> 3;
    const int bh = (bid & 7) + 8 * (j_ >> 4);
    const int q0 = (j_ & 15) * 128 + w * 32;

    const ushort* Qg = q_ws + (size_t)bh * S_ * 64;
    const ushort* Kg = k_ws + (size_t)bh * S_ * 64;
    const ushort* Vg = vt_ws + (size_t)bh * 64 * S_;

    s16x8 qf[4];
#pragma unroll
    for (int dc = 0; dc < 4; dc++)
        qf[dc] = *(const s16x8*)&Qg[(size_t)(q0 + l32) * 64 + dc * 16 + hi * 8];

    const int sr = t >> 3;
    const int sc = (t & 7) ^ (sr & 7);
    const ushort* kS = Kg + sr * 64 + sc * 8;
    const ushort* vS = Vg + (size_t)sr * 2048 + sc * 8;
    ushort* ldsK0 = &Kb[0][w * 512];
    ushort* ldsV0 = &Vb[0][w * 512];
    ushort* ldsK1 = &Kb[1][w * 512];
    ushort* ldsV1 = &Vb[1][w * 512];

    int fo[4];
#pragma unroll
    for (int c = 0; c < 4; c++)
        fo[c] = l32 * 64 + ((((c << 1) | hi) ^ (l32 & 7)) << 3);

    const f32x16 Z16 = {0.f,0.f,0.f,0.f,0.f,0.f,0.f,0.f,0.f,0.f,0.f,0.f,0.f,0.f,0.f,0.f};
    f32x16 o0 = Z16, o1 = Z16;
    float m_run = -1e30f, l_run = 0.f;

    gld16(ldsK0,        kS);
    gld16(ldsK0 + 2048, kS + 2048);
    gld16(ldsV0,        vS);
    gld16(ldsV0 + 2048, vS + (size_t)32 * 2048);
    __syncthreads();

    for (int kt = 0; kt < S_ / 64; ++kt) {
        const int cur = kt & 1;
        if (kt != S_ / 64 - 1) {
            const ushort* kn = kS + (kt + 1) * 4096;
            const ushort* vn = vS + (kt + 1) * 64;
            ushort* dK = cur ? ldsK0 : ldsK1;
            ushort* dV = cur ? ldsV0 : ldsV1;
            gld16(dK,        kn);
            gld16(dK + 2048, kn + 2048);
            gld16(dV,        vn);
            gld16(dV + 2048, vn + (size_t)32 * 2048);
        }
        const ushort* KB = &Kb[cur][0];
        const ushort* VB = &Vb[cur][0];

        f32x16 s0 = Z16, s1 = Z16;
#pragma unroll
        for (int dc = 0; dc < 4; dc++) {
            s16x8 k0 = *(const s16x8*)(KB + fo[dc]);
            s16x8 k1 = *(const s16x8*)(KB + 2048 + fo[dc]);
            s0 = MFMA32(k0, qf[dc], s0);
            s1 = MFMA32(k1, qf[dc], s1);
        }

        float m0 = fmaxf(s0[0], s1[0]), m1 = fmaxf(s0[1], s1[1]);
        float m2 = fmaxf(s0[2], s1[2]), m3 = fmaxf(s0[3], s1[3]);
#pragma unroll
        for (int r = 4; r < 16; r += 4) {
            m0 = fmaxf(m0, fmaxf(s0[r],     s1[r]));
            m1 = fmaxf(m1, fmaxf(s0[r + 1], s1[r + 1]));
            m2 = fmaxf(m2, fmaxf(s0[r + 2], s1[r + 2]));
            m3 = fmaxf(m3, fmaxf(s0[r + 3], s1[r + 3]));
        }
        float mx = fmaxf(fmaxf(m0, m1), fmaxf(m2, m3));
        mx = xmax32(mx);

        // T13 defer-max: rescale only when the tile max meaningfully grows
        if (__any(mx > m_run + 8.f)) {
            float mnew = fmaxf(m_run, mx);
            float alpha = exp2_fast(m_run - mnew);
            m_run = mnew;
            l_run *= alpha;
#pragma unroll
            for (int r = 0; r < 16; r++) { o0[r] *= alpha; o1[r] *= alpha; }
        }

        float ra = 0.f, rb = 0.f;
#pragma unroll
        for (int r = 0; r < 16; r++) {
            s0[r] = exp2_fast(s0[r] - m_run); ra += s0[r];
            s1[r] = exp2_fast(s1[r] - m_run); rb += s1[r];
        }
        l_run += xadd32(ra + rb);

#pragma unroll
        for (int ks = 0; ks < 2; ks++) {
            const f32x16& p = ks ? s1 : s0;
            uint32_t u0 = cvtpk(p[0], p[1]),   u2 = cvtpk(p[4], p[5]);
            plswap(u0, u2);
            uint32_t u1 = cvtpk(p[2], p[3]),   u3 = cvtpk(p[6], p[7]);
            plswap(u1, u3);
            uint32_t w0 = cvtpk(p[8], p[9]),   w2 = cvtpk(p[12], p[13]);
            plswap(w0, w2);
            uint32_t w1 = cvtpk(p[10], p[11]), w3 = cvtpk(p[14], p[15]);
            plswap(w1, w3);
            union { uint32_t u[4]; s16x8 h; } F0, F1;
            F0.u[0] = u0; F0.u[1] = u1; F0.u[2] = u2; F0.u[3] = u3;
            F1.u[0] = w0; F1.u[1] = w1; F1.u[2] = w2; F1.u[3] = w3;

            const int kc0 = ks * 2, kc1 = ks * 2 + 1;
            s16x8 v00 = *(const s16x8*)(VB + fo[kc0]);
            s16x8 v01 = *(const s16x8*)(VB + 2048 + fo[kc0]);
            s16x8 v10 = *(const s16x8*)(VB + fo[kc1]);
            s16x8 v11 = *(const s16x8*)(VB + 2048 + fo[kc1]);
            o0 = MFMA32(v00, F0.h, o0); o1 = MFMA32(v01, F0.h, o1);
            o0 = MFMA32(v10, F1.h, o0); o1 = MFMA32(v11, F1.h, o1);
        }

        __syncthreads();
    }

    float inv = 1.0f / l_run;
#pragma unroll
    for (int r = 0; r < 16; r++) {
        int d0 = (r & 3) + 8 * (r >> 2) + 4 * hi;
        obuf[w][l32][d0]      = f2bf(o0[r] * inv);
        obuf[w][l32][32 + d0] = f2bf(o1[r] * inv);
    }
    asm volatile("s_waitcnt lgkmcnt(0)" ::: "memory");
    __builtin_amdgcn_sched_barrier(0);
    int b_ = bh >> 4, h = bh & 15;
    ushort* gp = ctx + ((size_t)(b_ * 2048 + q0 + l32)) * 1024 + h * 64 + hi * 32;
#pragma unroll
    for (int c = 0; c < 4; c++)
        *(s16x8*)(gp + c * 8) = *(const s16x8*)&obuf[w][l32][hi * 32 + c * 8];
}

extern "C" void kernel_launch(void* const* d_in, const int* in_sizes, int n_in,
                              void* d_out, int out_size, void* d_ws, size_t ws_size,
                              hipStream_t stream) {
    const float* X  = (const float*)d_in[0];
    const float* Wq = (const float*)d_in[1];
    const float* bq = (const float*)d_in[2];
    const float* Wk = (const float*)d_in[3];
    const float* bk = (const float*)d_in[4];
    const float* Wv = (const float*)d_in[5];
    const float* bv = (const float*)d_in[6];
    const float* Wo = (const float*)d_in[7];
    const float* bo = (const float*)d_in[8];
    float* out = (float*)d_out;

    // ws (MiB): wtq@0(2) wtk@2(2) wtv@4(2) wto@6(2) qws@8(8) kws@16(8)
    // ctx@24(8) = 32 MiB. d_out hosts V^T bf16 @0 (8 MiB) + Xbf16 @8MiB (8 MiB):
    // both dead before the final GEMM overwrites d_out.
    char* ws = (char*)d_ws;
    ushort* wtq  = (ushort*)(ws);
    ushort* wtk  = (ushort*)(ws + ((size_t)2 << 20));
    ushort* wtv  = (ushort*)(ws + ((size_t)4 << 20));
    ushort* wto  = (ushort*)(ws + ((size_t)6 << 20));
    ushort* qws  = (ushort*)(ws + ((size_t)8 << 20));
    ushort* kws  = (ushort*)(ws + ((size_t)16 << 20));
    ushort* ctx  = (ushort*)(ws + ((size_t)24 << 20));
    ushort* vtws = (ushort*)d_out;
    ushort* xbf  = (ushort*)d_out + ((size_t)4 << 20);  // +8 MiB

    transpose_k4<<<dim3(32, 32, 4), dim3(32, 8), 0, stream>>>(Wq, Wk, Wv, Wo,
                                                              wtq, wtk, wtv, wto);
    cast_bf16<<<2048, 256, 0, stream>>>(X, xbf);

    // fused QKV projection (modes 1/2/3), 256^2 tiles
    gemm256<<<dim3(4, 16, 3), 512, 0, stream>>>(xbf, wtq, wtk, wtv, bq, bk, bv,
                                                qws, kws, vtws, 1);

    attn<<<dim3(512), 256, 0, stream>>>(qws, kws, vtws, ctx);

    // output projection (mode 0)
    gemm256<<<dim3(4, 16, 1), 512, 0, stream>>>(ctx, wto, wto, wto, bo, bo, bo,
                                                out, out, out, 0);
}

// Round 9
// 201.847 us; speedup vs baseline: 1.0661x; 1.0661x over previous
//
#include <hip/hip_runtime.h>
#include <stdint.h>

#define S_ 2048
#define H_ 16

typedef short s16x8 __attribute__((ext_vector_type(8)));
typedef float f32x4 __attribute__((ext_vector_type(4)));
typedef float f32x16 __attribute__((ext_vector_type(16)));

__device__ __forceinline__ ushort f2bf(float f) {
    union { float f; uint32_t u; } v; v.f = f;
    uint32_t r = v.u + 0x7fffu + ((v.u >> 16) & 1u);
    return (ushort)(r >> 16);
}
__device__ __forceinline__ uint32_t cvtpk(float a, float b) {
    uint32_t r;
    asm("v_cvt_pk_bf16_f32 %0, %1, %2" : "=v"(r) : "v"(a), "v"(b));
    return r;
}
__device__ __forceinline__ void plswap(uint32_t& a, uint32_t& b) {
    auto r = __builtin_amdgcn_permlane32_swap((int)a, (int)b, false, false);
    a = (uint32_t)r[0];
    b = (uint32_t)r[1];
}
__device__ __forceinline__ float xmax32(float x) {
    uint32_t a = __float_as_uint(x), b = a;
    plswap(a, b);
    return fmaxf(__uint_as_float(a), __uint_as_float(b));
}
__device__ __forceinline__ float xadd32(float x) {
    uint32_t a = __float_as_uint(x), b = a;
    plswap(a, b);
    return __uint_as_float(a) + __uint_as_float(b);
}
__device__ __forceinline__ float exp2_fast(float x) {
    float r;
    asm("v_exp_f32 %0, %1" : "=v"(r) : "v"(x));
    return r;
}

// async global->LDS, 16B per lane. LDS dest = wave-uniform base + lane*16.
__device__ __forceinline__ void gld16(ushort* lds, const ushort* g) {
    auto* gp = reinterpret_cast<uint32_t __attribute__((address_space(1)))*>(
        reinterpret_cast<uintptr_t>(g));
    auto* lp = reinterpret_cast<uint32_t __attribute__((address_space(3)))*>(
        reinterpret_cast<uintptr_t>(lds));
    __builtin_amdgcn_global_load_lds(gp, lp, 16, 0, 0);
}

// ---- X fp32 -> bf16 ----
__global__ void cast_bf16(const float* __restrict__ src, ushort* __restrict__ dst) {
    size_t i = ((size_t)blockIdx.x * 256 + threadIdx.x) * 8;
    float4 x = *(const float4*)(src + i);
    float4 y = *(const float4*)(src + i + 4);
    s16x8 r;
    r[0] = (short)f2bf(x.x); r[1] = (short)f2bf(x.y);
    r[2] = (short)f2bf(x.z); r[3] = (short)f2bf(x.w);
    r[4] = (short)f2bf(y.x); r[5] = (short)f2bf(y.y);
    r[6] = (short)f2bf(y.z); r[7] = (short)f2bf(y.w);
    *(s16x8*)(dst + i) = r;
}

// ---- weight prep: dst[n*1024+k] = bf16(src[k*1024+n]) ----
__global__ void transpose_k4(const float* __restrict__ s0, const float* __restrict__ s1,
                             const float* __restrict__ s2, const float* __restrict__ s3,
                             ushort* __restrict__ d0, ushort* __restrict__ d1,
                             ushort* __restrict__ d2, ushort* __restrict__ d3) {
    const int z = blockIdx.z;
    const float* src = (z == 0) ? s0 : (z == 1) ? s1 : (z == 2) ? s2 : s3;
    ushort* dst      = (z == 0) ? d0 : (z == 1) ? d1 : (z == 2) ? d2 : d3;
    __shared__ ushort t[32][33];
    int bx = blockIdx.x * 32, by = blockIdx.y * 32;
    int x = threadIdx.x;
    for (int y = threadIdx.y; y < 32; y += 8)
        t[y][x] = f2bf(src[(size_t)(by + y) * 1024 + bx + x]);
    __syncthreads();
    for (int y = threadIdx.y; y < 32; y += 8)
        dst[(size_t)(bx + y) * 1024 + by + x] = t[x][y];
}

// ---------------- GEMM: C[m,n] = A[M,K] @ Bt[N,K]^T + bias(fp32) ------------
// R5-proven data path (BK=32, linear LDS, m97 2-barrier loop).
// NEW (T1, index-only): XCD swizzle — each XCD owns 4 contiguous by-rows:
// 1MB A-panel + 2MB B resident in its 4MB L2 (unswizzled: full 8MB A thrash).
// mode 0: fp32 out[m*1024+n]
// mode 1: Q bf16 out[((b*16+h)*2048+s)*64+d] = v * 0.125*log2(e)  (exp2 domain)
// mode 2: K bf16 same layout
// mode 3: Vt bf16 out[((b*16+h)*64+d)*2048+s] = v (LDS transpose, coalesced)
__global__ void gemm_bt(const ushort* __restrict__ A,
                        const ushort* __restrict__ Bt0, const ushort* __restrict__ Bt1,
                        const ushort* __restrict__ Bt2,
                        const float* __restrict__ bi0, const float* __restrict__ bi1,
                        const float* __restrict__ bi2,
                        void* __restrict__ o0, void* __restrict__ o1,
                        void* __restrict__ o2,
                        int mode0) {
    const int z = blockIdx.z;
    const ushort* Bt  = (z == 0) ? Bt0 : (z == 1) ? Bt1 : Bt2;
    const float* bia  = (z == 0) ? bi0 : (z == 1) ? bi1 : bi2;
    void* out         = (z == 0) ? o0  : (z == 1) ? o1  : o2;
    const int mode = mode0 + z;

    __shared__ __align__(16) ushort SMEM[2][4096];  // Asm | Bsm
    ushort* Asm = &SMEM[0][0];
    ushort* Bsm = &SMEM[1][0];

    const int t = threadIdx.x;
    const int lane = t & 63, w = t >> 6;
    const int wm = w >> 1, wn = w & 1;
    const int quad = lane >> 4, l16 = lane & 15;

    // T1 XCD swizzle: 256 blocks/z, round-robin dispatch -> XCD = bid&7.
    // swz = (bid&7)*32 + (bid>>3): XCD k owns by in [4k,4k+4) (all bx).
    const int bid = blockIdx.y * 8 + blockIdx.x;
    const int swz = (bid & 7) * 32 + (bid >> 3);
    const int m0 = (swz >> 3) * 128, n0 = (swz & 7) * 128;
    const int K = 1024;

    const f32x4 FZ = {0.f, 0.f, 0.f, 0.f};
    f32x4 acc[4][4];
#pragma unroll
    for (int i = 0; i < 4; i++)
#pragma unroll
        for (int j = 0; j < 4; j++) acc[i][j] = FZ;

    const ushort* Ap = A  + (size_t)(m0 + (t >> 2)) * K + (t & 3) * 8;
    const ushort* Bp = Bt + (size_t)(n0 + (t >> 2)) * K + (t & 3) * 8;
    ushort* AsmW = Asm + w * 512;
    ushort* BsmW = Bsm + w * 512;

    for (int kt = 0; kt < K / 32; ++kt) {
        __syncthreads();
        gld16(AsmW,        Ap + kt * 32);
        gld16(AsmW + 2048, Ap + (size_t)64 * K + kt * 32);
        gld16(BsmW,        Bp + kt * 32);
        gld16(BsmW + 2048, Bp + (size_t)64 * K + kt * 32);
        __syncthreads();

        s16x8 a[4], b[4];
#pragma unroll
        for (int i = 0; i < 4; i++) {
            int row = wm * 64 + i * 16 + l16;
            a[i] = *(const s16x8*)((const char*)Asm + row * 64 + quad * 16);
        }
#pragma unroll
        for (int j = 0; j < 4; j++) {
            int row = wn * 64 + j * 16 + l16;
            b[j] = *(const s16x8*)((const char*)Bsm + row * 64 + quad * 16);
        }
#pragma unroll
        for (int i = 0; i < 4; i++)
#pragma unroll
            for (int j = 0; j < 4; j++)
                acc[i][j] = __builtin_amdgcn_mfma_f32_16x16x32_bf16(a[i], b[j], acc[i][j], 0, 0, 0);
    }

    if (mode == 3) {
        // V^T epilogue: transpose 128x128 tile through LDS (XOR-swizzled),
        // then coalesced 16B row stores. (R5-verified.)
        ushort* T = Asm;
        const int b_ = m0 >> 11;
        const int s_base = m0 & 2047;
        __syncthreads();
#pragma unroll
        for (int half = 0; half < 2; ++half) {
            if (wn == half) {
#pragma unroll
                for (int j = 0; j < 4; j++) {
                    int nl = j * 16 + l16;
                    float bv = bia[n0 + half * 64 + nl];
#pragma unroll
                    for (int i = 0; i < 4; i++) {
#pragma unroll
                        for (int r = 0; r < 4; r++) {
                            int ml = wm * 64 + i * 16 + quad * 4 + r;
                            T[nl * 128 + (ml ^ ((nl & 15) << 3))] = f2bf(acc[i][j][r] + bv);
                        }
                    }
                }
            }
            __syncthreads();
            {
                int row = t >> 2, cg = (t & 3) * 32;
                int ng = n0 + half * 64 + row;
                int h = ng >> 6, d = ng & 63;
                ushort* op = (ushort*)out + ((size_t)((b_ * 16 + h) * 64 + d)) * 2048 + s_base + cg;
#pragma unroll
                for (int c = 0; c < 4; c++) {
                    int col = (cg + c * 8) ^ ((row & 15) << 3);
                    *(s16x8*)(op + c * 8) = *(const s16x8*)(T + row * 128 + col);
                }
            }
            __syncthreads();
        }
        return;
    }

#pragma unroll
    for (int j = 0; j < 4; j++) {
        int n = n0 + wn * 64 + j * 16 + l16;
        float bv = bia[n];
#pragma unroll
        for (int i = 0; i < 4; i++) {
#pragma unroll
            for (int r = 0; r < 4; r++) {
                int m = m0 + wm * 64 + i * 16 + quad * 4 + r;
                float v = acc[i][j][r] + bv;
                if (mode == 0) {
                    ((float*)out)[(size_t)m * 1024 + n] = v;
                } else {
                    int b_ = m >> 11, s = m & 2047;
                    int h = n >> 6, d = n & 63;
                    if (mode == 1)  // 0.125*log2(e): attn softmax runs in exp2 domain
                        ((ushort*)out)[((size_t)(b_ * 16 + h) * 2048 + s) * 64 + d] = f2bf(v * 0.18033688011112042f);
                    else
                        ((ushort*)out)[((size_t)(b_ * 16 + h) * 2048 + s) * 64 + d] = f2bf(v);
                }
            }
        }
    }
}

// ---------------- MFMA flash attention: LDS-staged 2-phase pipeline ----------
// R6-proven version (defer-max, passed absmax 4.88e-4). Maxless variant is
// QUARANTINED: R7/R8 bisect showed it alone costs ~5.7e-3 absmax (mechanism
// unresolved — do not retry without offline numeric study).
// NEW (T5): s_setprio(1) around MFMA clusters (catalog m191: +4-7% attn).
#define MFMA32(a, b, c) __builtin_amdgcn_mfma_f32_32x32x16_bf16(a, b, c, 0, 0, 0)

__global__ __launch_bounds__(256, 2) void attn(const ushort* __restrict__ q_ws,
                                               const ushort* __restrict__ k_ws,
                                               const ushort* __restrict__ vt_ws,
                                               ushort* __restrict__ ctx) {
    __shared__ __align__(16) ushort Kb[2][4096];
    __shared__ __align__(16) ushort Vb[2][4096];
    __shared__ ushort obuf[4][32][72];

    const int t = threadIdx.x, lane = t & 63, w = t >> 6;
    const int l32 = lane & 31, hi = lane >> 5;

    const int bid = blockIdx.x;
    const int j_ = bid >> 3;
    const int bh = (bid & 7) + 8 * (j_ >> 4);
    const int q0 = (j_ & 15) * 128 + w * 32;

    const ushort* Qg = q_ws + (size_t)bh * S_ * 64;
    const ushort* Kg = k_ws + (size_t)bh * S_ * 64;
    const ushort* Vg = vt_ws + (size_t)bh * 64 * S_;

    s16x8 qf[4];
#pragma unroll
    for (int dc = 0; dc < 4; dc++)
        qf[dc] = *(const s16x8*)&Qg[(size_t)(q0 + l32) * 64 + dc * 16 + hi * 8];

    const int sr = t >> 3;
    const int sc = (t & 7) ^ (sr & 7);
    const ushort* kS = Kg + sr * 64 + sc * 8;
    const ushort* vS = Vg + (size_t)sr * 2048 + sc * 8;
    ushort* ldsK0 = &Kb[0][w * 512];
    ushort* ldsV0 = &Vb[0][w * 512];
    ushort* ldsK1 = &Kb[1][w * 512];
    ushort* ldsV1 = &Vb[1][w * 512];

    int fo[4];
#pragma unroll
    for (int c = 0; c < 4; c++)
        fo[c] = l32 * 64 + ((((c << 1) | hi) ^ (l32 & 7)) << 3);

    const f32x16 Z16 = {0.f,0.f,0.f,0.f,0.f,0.f,0.f,0.f,0.f,0.f,0.f,0.f,0.f,0.f,0.f,0.f};
    f32x16 o0 = Z16, o1 = Z16;
    float m_run = -1e30f, l_run = 0.f;

    gld16(ldsK0,        kS);
    gld16(ldsK0 + 2048, kS + 2048);
    gld16(ldsV0,        vS);
    gld16(ldsV0 + 2048, vS + (size_t)32 * 2048);
    __syncthreads();

    for (int kt = 0; kt < S_ / 64; ++kt) {
        const int cur = kt & 1;
        if (kt != S_ / 64 - 1) {
            const ushort* kn = kS + (kt + 1) * 4096;
            const ushort* vn = vS + (kt + 1) * 64;
            ushort* dK = cur ? ldsK0 : ldsK1;
            ushort* dV = cur ? ldsV0 : ldsV1;
            gld16(dK,        kn);
            gld16(dK + 2048, kn + 2048);
            gld16(dV,        vn);
            gld16(dV + 2048, vn + (size_t)32 * 2048);
        }
        const ushort* KB = &Kb[cur][0];
        const ushort* VB = &Vb[cur][0];

        f32x16 s0 = Z16, s1 = Z16;
        __builtin_amdgcn_s_setprio(1);
#pragma unroll
        for (int dc = 0; dc < 4; dc++) {
            s16x8 k0 = *(const s16x8*)(KB + fo[dc]);
            s16x8 k1 = *(const s16x8*)(KB + 2048 + fo[dc]);
            s0 = MFMA32(k0, qf[dc], s0);
            s1 = MFMA32(k1, qf[dc], s1);
        }
        __builtin_amdgcn_s_setprio(0);

        float m0 = fmaxf(s0[0], s1[0]), m1 = fmaxf(s0[1], s1[1]);
        float m2 = fmaxf(s0[2], s1[2]), m3 = fmaxf(s0[3], s1[3]);
#pragma unroll
        for (int r = 4; r < 16; r += 4) {
            m0 = fmaxf(m0, fmaxf(s0[r],     s1[r]));
            m1 = fmaxf(m1, fmaxf(s0[r + 1], s1[r + 1]));
            m2 = fmaxf(m2, fmaxf(s0[r + 2], s1[r + 2]));
            m3 = fmaxf(m3, fmaxf(s0[r + 3], s1[r + 3]));
        }
        float mx = fmaxf(fmaxf(m0, m1), fmaxf(m2, m3));
        mx = xmax32(mx);

        // T13 defer-max: rescale only when the tile max meaningfully grows
        if (__any(mx > m_run + 8.f)) {
            float mnew = fmaxf(m_run, mx);
            float alpha = exp2_fast(m_run - mnew);
            m_run = mnew;
            l_run *= alpha;
#pragma unroll
            for (int r = 0; r < 16; r++) { o0[r] *= alpha; o1[r] *= alpha; }
        }

        float ra = 0.f, rb = 0.f;
#pragma unroll
        for (int r = 0; r < 16; r++) {
            s0[r] = exp2_fast(s0[r] - m_run); ra += s0[r];
            s1[r] = exp2_fast(s1[r] - m_run); rb += s1[r];
        }
        l_run += xadd32(ra + rb);

#pragma unroll
        for (int ks = 0; ks < 2; ks++) {
            const f32x16& p = ks ? s1 : s0;
            uint32_t u0 = cvtpk(p[0], p[1]),   u2 = cvtpk(p[4], p[5]);
            plswap(u0, u2);
            uint32_t u1 = cvtpk(p[2], p[3]),   u3 = cvtpk(p[6], p[7]);
            plswap(u1, u3);
            uint32_t w0 = cvtpk(p[8], p[9]),   w2 = cvtpk(p[12], p[13]);
            plswap(w0, w2);
            uint32_t w1 = cvtpk(p[10], p[11]), w3 = cvtpk(p[14], p[15]);
            plswap(w1, w3);
            union { uint32_t u[4]; s16x8 h; } F0, F1;
            F0.u[0] = u0; F0.u[1] = u1; F0.u[2] = u2; F0.u[3] = u3;
            F1.u[0] = w0; F1.u[1] = w1; F1.u[2] = w2; F1.u[3] = w3;

            const int kc0 = ks * 2, kc1 = ks * 2 + 1;
            s16x8 v00 = *(const s16x8*)(VB + fo[kc0]);
            s16x8 v01 = *(const s16x8*)(VB + 2048 + fo[kc0]);
            s16x8 v10 = *(const s16x8*)(VB + fo[kc1]);
            s16x8 v11 = *(const s16x8*)(VB + 2048 + fo[kc1]);
            __builtin_amdgcn_s_setprio(1);
            o0 = MFMA32(v00, F0.h, o0); o1 = MFMA32(v01, F0.h, o1);
            o0 = MFMA32(v10, F1.h, o0); o1 = MFMA32(v11, F1.h, o1);
            __builtin_amdgcn_s_setprio(0);
        }

        __syncthreads();
    }

    float inv = 1.0f / l_run;
#pragma unroll
    for (int r = 0; r < 16; r++) {
        int d0 = (r & 3) + 8 * (r >> 2) + 4 * hi;
        obuf[w][l32][d0]      = f2bf(o0[r] * inv);
        obuf[w][l32][32 + d0] = f2bf(o1[r] * inv);
    }
    asm volatile("s_waitcnt lgkmcnt(0)" ::: "memory");
    __builtin_amdgcn_sched_barrier(0);
    int b_ = bh >> 4, h = bh & 15;
    ushort* gp = ctx + ((size_t)(b_ * 2048 + q0 + l32)) * 1024 + h * 64 + hi * 32;
#pragma unroll
    for (int c = 0; c < 4; c++)
        *(s16x8*)(gp + c * 8) = *(const s16x8*)&obuf[w][l32][hi * 32 + c * 8];
}

extern "C" void kernel_launch(void* const* d_in, const int* in_sizes, int n_in,
                              void* d_out, int out_size, void* d_ws, size_t ws_size,
                              hipStream_t stream) {
    const float* X  = (const float*)d_in[0];
    const float* Wq = (const float*)d_in[1];
    const float* bq = (const float*)d_in[2];
    const float* Wk = (const float*)d_in[3];
    const float* bk = (const float*)d_in[4];
    const float* Wv = (const float*)d_in[5];
    const float* bv = (const float*)d_in[6];
    const float* Wo = (const float*)d_in[7];
    const float* bo = (const float*)d_in[8];
    float* out = (float*)d_out;

    // ws (MiB): wtq@0(2) wtk@2(2) wtv@4(2) wto@6(2) qws@8(8) kws@16(8)
    // ctx@24(8) = 32 MiB. d_out hosts V^T bf16 @0 (8 MiB) + Xbf16 @8MiB (8 MiB):
    // both dead before the final GEMM overwrites d_out.
    char* ws = (char*)d_ws;
    ushort* wtq  = (ushort*)(ws);
    ushort* wtk  = (ushort*)(ws + ((size_t)2 << 20));
    ushort* wtv  = (ushort*)(ws + ((size_t)4 << 20));
    ushort* wto  = (ushort*)(ws + ((size_t)6 << 20));
    ushort* qws  = (ushort*)(ws + ((size_t)8 << 20));
    ushort* kws  = (ushort*)(ws + ((size_t)16 << 20));
    ushort* ctx  = (ushort*)(ws + ((size_t)24 << 20));
    ushort* vtws = (ushort*)d_out;
    ushort* xbf  = (ushort*)d_out + ((size_t)4 << 20);  // +8 MiB

    transpose_k4<<<dim3(32, 32, 4), dim3(32, 8), 0, stream>>>(Wq, Wk, Wv, Wo,
                                                              wtq, wtk, wtv, wto);
    cast_bf16<<<2048, 256, 0, stream>>>(X, xbf);

    // fused QKV projection (modes 1/2/3)
    gemm_bt<<<dim3(8, 32, 3), 256, 0, stream>>>(xbf, wtq, wtk, wtv, bq, bk, bv,
                                                qws, kws, vtws, 1);

    attn<<<dim3(512), 256, 0, stream>>>(qws, kws, vtws, ctx);

    // output projection (mode 0)
    gemm_bt<<<dim3(8, 32, 1), 256, 0, stream>>>(ctx, wto, wto, wto, bo, bo, bo,
                                                out, out, out, 0);
}

// Round 10
// 193.735 us; speedup vs baseline: 1.1107x; 1.0419x over previous
//
#include <hip/hip_runtime.h>
#include <stdint.h>

#define S_ 2048
#define H_ 16

typedef short s16x8 __attribute__((ext_vector_type(8)));
typedef float f32x4 __attribute__((ext_vector_type(4)));
typedef float f32x16 __attribute__((ext_vector_type(16)));

__device__ __forceinline__ ushort f2bf(float f) {
    union { float f; uint32_t u; } v; v.f = f;
    uint32_t r = v.u + 0x7fffu + ((v.u >> 16) & 1u);
    return (ushort)(r >> 16);
}
__device__ __forceinline__ uint32_t cvtpk(float a, float b) {
    uint32_t r;
    asm("v_cvt_pk_bf16_f32 %0, %1, %2" : "=v"(r) : "v"(a), "v"(b));
    return r;
}
__device__ __forceinline__ void plswap(uint32_t& a, uint32_t& b) {
    auto r = __builtin_amdgcn_permlane32_swap((int)a, (int)b, false, false);
    a = (uint32_t)r[0];
    b = (uint32_t)r[1];
}
__device__ __forceinline__ float xmax32(float x) {
    uint32_t a = __float_as_uint(x), b = a;
    plswap(a, b);
    return fmaxf(__uint_as_float(a), __uint_as_float(b));
}
__device__ __forceinline__ float xadd32(float x) {
    uint32_t a = __float_as_uint(x), b = a;
    plswap(a, b);
    return __uint_as_float(a) + __uint_as_float(b);
}
__device__ __forceinline__ float exp2_fast(float x) {
    float r;
    asm("v_exp_f32 %0, %1" : "=v"(r) : "v"(x));
    return r;
}

// async global->LDS, 16B per lane. LDS dest = wave-uniform base + lane*16.
__device__ __forceinline__ void gld16(ushort* lds, const ushort* g) {
    auto* gp = reinterpret_cast<uint32_t __attribute__((address_space(1)))*>(
        reinterpret_cast<uintptr_t>(g));
    auto* lp = reinterpret_cast<uint32_t __attribute__((address_space(3)))*>(
        reinterpret_cast<uintptr_t>(lds));
    __builtin_amdgcn_global_load_lds(gp, lp, 16, 0, 0);
}

// ---- X fp32 -> bf16 ----
__global__ void cast_bf16(const float* __restrict__ src, ushort* __restrict__ dst) {
    size_t i = ((size_t)blockIdx.x * 256 + threadIdx.x) * 8;
    float4 x = *(const float4*)(src + i);
    float4 y = *(const float4*)(src + i + 4);
    s16x8 r;
    r[0] = (short)f2bf(x.x); r[1] = (short)f2bf(x.y);
    r[2] = (short)f2bf(x.z); r[3] = (short)f2bf(x.w);
    r[4] = (short)f2bf(y.x); r[5] = (short)f2bf(y.y);
    r[6] = (short)f2bf(y.z); r[7] = (short)f2bf(y.w);
    *(s16x8*)(dst + i) = r;
}

// ---- weight prep: dst[n*1024+k] = bf16(src[k*1024+n]) ----
__global__ void transpose_k4(const float* __restrict__ s0, const float* __restrict__ s1,
                             const float* __restrict__ s2, const float* __restrict__ s3,
                             ushort* __restrict__ d0, ushort* __restrict__ d1,
                             ushort* __restrict__ d2, ushort* __restrict__ d3) {
    const int z = blockIdx.z;
    const float* src = (z == 0) ? s0 : (z == 1) ? s1 : (z == 2) ? s2 : s3;
    ushort* dst      = (z == 0) ? d0 : (z == 1) ? d1 : (z == 2) ? d2 : d3;
    __shared__ ushort t[32][33];
    int bx = blockIdx.x * 32, by = blockIdx.y * 32;
    int x = threadIdx.x;
    for (int y = threadIdx.y; y < 32; y += 8)
        t[y][x] = f2bf(src[(size_t)(by + y) * 1024 + bx + x]);
    __syncthreads();
    for (int y = threadIdx.y; y < 32; y += 8)
        dst[(size_t)(bx + y) * 1024 + by + x] = t[x][y];
}

// ---------------- GEMM: C[m,n] = A[M,K] @ Bt[N,K]^T + bias(fp32) ------------
// BK=64 variant (quarantine lifted: R7/R8 bisect showed maxless-attn alone
// reproduces R7's error; this kernel's audit is clean and its FLOP order is
// identical to the R5 BK=32 version -> expected bit-identical output).
// 16 iters x {stage 32KB, 2 barriers, 32 MFMA/wave} — half the barrier drains
// of BK=32. LDS 32KB -> 4 blocks/CU. Both-sides chunk-XOR bank swizzle:
// LDS[r][c] = global chunk c^(r&7); frag read ck = (gc ^ (l16&7))*8.
// T1 XCD swizzle (R9-proven): XCD k owns 4 contiguous by-rows.
// mode 0: fp32 out[m*1024+n]
// mode 1: Q bf16 out[((b*16+h)*2048+s)*64+d] = v * 0.125*log2(e)  (exp2 domain)
// mode 2: K bf16 same layout
// mode 3: Vt bf16 out[((b*16+h)*64+d)*2048+s] = v (LDS transpose, coalesced)
#define MFMA16(a, b, c) __builtin_amdgcn_mfma_f32_16x16x32_bf16(a, b, c, 0, 0, 0)

__global__ __launch_bounds__(256, 4) void gemm_bt(
        const ushort* __restrict__ A,
        const ushort* __restrict__ Bt0, const ushort* __restrict__ Bt1,
        const ushort* __restrict__ Bt2,
        const float* __restrict__ bi0, const float* __restrict__ bi1,
        const float* __restrict__ bi2,
        void* __restrict__ o0, void* __restrict__ o1, void* __restrict__ o2,
        int mode0) {
    const int z = blockIdx.z;
    const ushort* Bt  = (z == 0) ? Bt0 : (z == 1) ? Bt1 : Bt2;
    const float* bia  = (z == 0) ? bi0 : (z == 1) ? bi1 : bi2;
    void* out         = (z == 0) ? o0  : (z == 1) ? o1  : o2;
    const int mode = mode0 + z;

    __shared__ __align__(16) ushort Asm[128 * 64];  // 16KB
    __shared__ __align__(16) ushort Bsm[128 * 64];  // 16KB

    const int t = threadIdx.x;
    const int lane = t & 63, w = t >> 6;
    const int wm = w >> 1, wn = w & 1;
    const int quad = lane >> 4, l16 = lane & 15;

    // T1 XCD swizzle: 256 blocks/z, round-robin dispatch -> XCD = bid&7.
    const int bid = blockIdx.y * 8 + blockIdx.x;
    const int swz = (bid & 7) * 32 + (bid >> 3);
    const int m0 = (swz >> 3) * 128, n0 = (swz & 7) * 128;
    const int K = 1024;

    const f32x4 FZ = {0.f, 0.f, 0.f, 0.f};
    f32x4 acc[4][4];
#pragma unroll
    for (int i = 0; i < 4; i++)
#pragma unroll
        for (int j = 0; j < 4; j++) acc[i][j] = FZ;

    // staging: thread t covers rows rr+{0,32,64,96}, chunkpos t&7;
    // source chunk = (t&7) ^ (rr&7)  (row&7 == rr&7 for all groups)
    const int rr = t >> 3;
    const int sc = (t & 7) ^ (rr & 7);
    const ushort* Ap = A  + (size_t)(m0 + rr) * K + sc * 8;
    const ushort* Bp = Bt + (size_t)(n0 + rr) * K + sc * 8;
    ushort* AsmW = Asm + w * 512;
    ushort* BsmW = Bsm + w * 512;

    const int fx = l16 & 7;

    for (int kt = 0; kt < 16; ++kt) {
        __syncthreads();  // prior iteration's fragment reads done
        const int o = kt * 64;
#pragma unroll
        for (int g = 0; g < 4; g++) {
            gld16(AsmW + g * 2048, Ap + (size_t)(g * 32) * K + o);
            gld16(BsmW + g * 2048, Bp + (size_t)(g * 32) * K + o);
        }
        __syncthreads();  // vmcnt(0) drain: tile staged

#pragma unroll
        for (int ks = 0; ks < 2; ks++) {
            const int ck = (((ks << 2) | quad) ^ fx) * 8;
            s16x8 a[4], b[4];
#pragma unroll
            for (int i = 0; i < 4; i++)
                a[i] = *(const s16x8*)&Asm[(wm * 64 + i * 16 + l16) * 64 + ck];
#pragma unroll
            for (int j = 0; j < 4; j++)
                b[j] = *(const s16x8*)&Bsm[(wn * 64 + j * 16 + l16) * 64 + ck];
#pragma unroll
            for (int i = 0; i < 4; i++)
#pragma unroll
                for (int j = 0; j < 4; j++)
                    acc[i][j] = MFMA16(a[i], b[j], acc[i][j]);
        }
    }

    if (mode == 3) {
        // V^T epilogue: transpose 128x128 tile through LDS (XOR-swizzled),
        // then coalesced 16B row stores. (R5-verified.)
        ushort* T = Asm;  // 16KB: one 64(n) x 128(m) half-tile
        const int b_ = m0 >> 11;
        const int s_base = m0 & 2047;
        __syncthreads();
#pragma unroll
        for (int half = 0; half < 2; ++half) {
            if (wn == half) {
#pragma unroll
                for (int j = 0; j < 4; j++) {
                    int nl = j * 16 + l16;
                    float bv = bia[n0 + half * 64 + nl];
#pragma unroll
                    for (int i = 0; i < 4; i++) {
#pragma unroll
                        for (int r = 0; r < 4; r++) {
                            int ml = wm * 64 + i * 16 + quad * 4 + r;
                            T[nl * 128 + (ml ^ ((nl & 15) << 3))] = f2bf(acc[i][j][r] + bv);
                        }
                    }
                }
            }
            __syncthreads();
            {
                int row = t >> 2, cg = (t & 3) * 32;
                int ng = n0 + half * 64 + row;
                int h = ng >> 6, d = ng & 63;
                ushort* op = (ushort*)out + ((size_t)((b_ * 16 + h) * 64 + d)) * 2048 + s_base + cg;
#pragma unroll
                for (int c = 0; c < 4; c++) {
                    int col = (cg + c * 8) ^ ((row & 15) << 3);
                    *(s16x8*)(op + c * 8) = *(const s16x8*)(T + row * 128 + col);
                }
            }
            __syncthreads();
        }
        return;
    }

#pragma unroll
    for (int j = 0; j < 4; j++) {
        int n = n0 + wn * 64 + j * 16 + l16;
        float bv = bia[n];
#pragma unroll
        for (int i = 0; i < 4; i++) {
#pragma unroll
            for (int r = 0; r < 4; r++) {
                int m = m0 + wm * 64 + i * 16 + quad * 4 + r;
                float v = acc[i][j][r] + bv;
                if (mode == 0) {
                    ((float*)out)[(size_t)m * 1024 + n] = v;
                } else {
                    int b_ = m >> 11, s = m & 2047;
                    int h = n >> 6, d = n & 63;
                    if (mode == 1)  // 0.125*log2(e): attn softmax runs in exp2 domain
                        ((ushort*)out)[((size_t)(b_ * 16 + h) * 2048 + s) * 64 + d] = f2bf(v * 0.18033688011112042f);
                    else
                        ((ushort*)out)[((size_t)(b_ * 16 + h) * 2048 + s) * 64 + d] = f2bf(v);
                }
            }
        }
    }
}

// ---------------- MFMA flash attention: LDS-staged 2-phase pipeline ----------
// R9-verbatim (defer-max + setprio; passed 58.0us, absmax 4.88e-4).
// Maxless softmax QUARANTINED (R7/R8 bisect: ~5.7e-3 absmax alone).
#define MFMA32(a, b, c) __builtin_amdgcn_mfma_f32_32x32x16_bf16(a, b, c, 0, 0, 0)

__global__ __launch_bounds__(256, 2) void attn(const ushort* __restrict__ q_ws,
                                               const ushort* __restrict__ k_ws,
                                               const ushort* __restrict__ vt_ws,
                                               ushort* __restrict__ ctx) {
    __shared__ __align__(16) ushort Kb[2][4096];
    __shared__ __align__(16) ushort Vb[2][4096];
    __shared__ ushort obuf[4][32][72];

    const int t = threadIdx.x, lane = t & 63, w = t >> 6;
    const int l32 = lane & 31, hi = lane >> 5;

    const int bid = blockIdx.x;
    const int j_ = bid >> 3;
    const int bh = (bid & 7) + 8 * (j_ >> 4);
    const int q0 = (j_ & 15) * 128 + w * 32;

    const ushort* Qg = q_ws + (size_t)bh * S_ * 64;
    const ushort* Kg = k_ws + (size_t)bh * S_ * 64;
    const ushort* Vg = vt_ws + (size_t)bh * 64 * S_;

    s16x8 qf[4];
#pragma unroll
    for (int dc = 0; dc < 4; dc++)
        qf[dc] = *(const s16x8*)&Qg[(size_t)(q0 + l32) * 64 + dc * 16 + hi * 8];

    const int sr = t >> 3;
    const int sc = (t & 7) ^ (sr & 7);
    const ushort* kS = Kg + sr * 64 + sc * 8;
    const ushort* vS = Vg + (size_t)sr * 2048 + sc * 8;
    ushort* ldsK0 = &Kb[0][w * 512];
    ushort* ldsV0 = &Vb[0][w * 512];
    ushort* ldsK1 = &Kb[1][w * 512];
    ushort* ldsV1 = &Vb[1][w * 512];

    int fo[4];
#pragma unroll
    for (int c = 0; c < 4; c++)
        fo[c] = l32 * 64 + ((((c << 1) | hi) ^ (l32 & 7)) << 3);

    const f32x16 Z16 = {0.f,0.f,0.f,0.f,0.f,0.f,0.f,0.f,0.f,0.f,0.f,0.f,0.f,0.f,0.f,0.f};
    f32x16 o0 = Z16, o1 = Z16;
    float m_run = -1e30f, l_run = 0.f;

    gld16(ldsK0,        kS);
    gld16(ldsK0 + 2048, kS + 2048);
    gld16(ldsV0,        vS);
    gld16(ldsV0 + 2048, vS + (size_t)32 * 2048);
    __syncthreads();

    for (int kt = 0; kt < S_ / 64; ++kt) {
        const int cur = kt & 1;
        if (kt != S_ / 64 - 1) {
            const ushort* kn = kS + (kt + 1) * 4096;
            const ushort* vn = vS + (kt + 1) * 64;
            ushort* dK = cur ? ldsK0 : ldsK1;
            ushort* dV = cur ? ldsV0 : ldsV1;
            gld16(dK,        kn);
            gld16(dK + 2048, kn + 2048);
            gld16(dV,        vn);
            gld16(dV + 2048, vn + (size_t)32 * 2048);
        }
        const ushort* KB = &Kb[cur][0];
        const ushort* VB = &Vb[cur][0];

        f32x16 s0 = Z16, s1 = Z16;
        __builtin_amdgcn_s_setprio(1);
#pragma unroll
        for (int dc = 0; dc < 4; dc++) {
            s16x8 k0 = *(const s16x8*)(KB + fo[dc]);
            s16x8 k1 = *(const s16x8*)(KB + 2048 + fo[dc]);
            s0 = MFMA32(k0, qf[dc], s0);
            s1 = MFMA32(k1, qf[dc], s1);
        }
        __builtin_amdgcn_s_setprio(0);

        float m0 = fmaxf(s0[0], s1[0]), m1 = fmaxf(s0[1], s1[1]);
        float m2 = fmaxf(s0[2], s1[2]), m3 = fmaxf(s0[3], s1[3]);
#pragma unroll
        for (int r = 4; r < 16; r += 4) {
            m0 = fmaxf(m0, fmaxf(s0[r],     s1[r]));
            m1 = fmaxf(m1, fmaxf(s0[r + 1], s1[r + 1]));
            m2 = fmaxf(m2, fmaxf(s0[r + 2], s1[r + 2]));
            m3 = fmaxf(m3, fmaxf(s0[r + 3], s1[r + 3]));
        }
        float mx = fmaxf(fmaxf(m0, m1), fmaxf(m2, m3));
        mx = xmax32(mx);

        // T13 defer-max: rescale only when the tile max meaningfully grows
        if (__any(mx > m_run + 8.f)) {
            float mnew = fmaxf(m_run, mx);
            float alpha = exp2_fast(m_run - mnew);
            m_run = mnew;
            l_run *= alpha;
#pragma unroll
            for (int r = 0; r < 16; r++) { o0[r] *= alpha; o1[r] *= alpha; }
        }

        float ra = 0.f, rb = 0.f;
#pragma unroll
        for (int r = 0; r < 16; r++) {
            s0[r] = exp2_fast(s0[r] - m_run); ra += s0[r];
            s1[r] = exp2_fast(s1[r] - m_run); rb += s1[r];
        }
        l_run += xadd32(ra + rb);

#pragma unroll
        for (int ks = 0; ks < 2; ks++) {
            const f32x16& p = ks ? s1 : s0;
            uint32_t u0 = cvtpk(p[0], p[1]),   u2 = cvtpk(p[4], p[5]);
            plswap(u0, u2);
            uint32_t u1 = cvtpk(p[2], p[3]),   u3 = cvtpk(p[6], p[7]);
            plswap(u1, u3);
            uint32_t w0 = cvtpk(p[8], p[9]),   w2 = cvtpk(p[12], p[13]);
            plswap(w0, w2);
            uint32_t w1 = cvtpk(p[10], p[11]), w3 = cvtpk(p[14], p[15]);
            plswap(w1, w3);
            union { uint32_t u[4]; s16x8 h; } F0, F1;
            F0.u[0] = u0; F0.u[1] = u1; F0.u[2] = u2; F0.u[3] = u3;
            F1.u[0] = w0; F1.u[1] = w1; F1.u[2] = w2; F1.u[3] = w3;

            const int kc0 = ks * 2, kc1 = ks * 2 + 1;
            s16x8 v00 = *(const s16x8*)(VB + fo[kc0]);
            s16x8 v01 = *(const s16x8*)(VB + 2048 + fo[kc0]);
            s16x8 v10 = *(const s16x8*)(VB + fo[kc1]);
            s16x8 v11 = *(const s16x8*)(VB + 2048 + fo[kc1]);
            __builtin_amdgcn_s_setprio(1);
            o0 = MFMA32(v00, F0.h, o0); o1 = MFMA32(v01, F0.h, o1);
            o0 = MFMA32(v10, F1.h, o0); o1 = MFMA32(v11, F1.h, o1);
            __builtin_amdgcn_s_setprio(0);
        }

        __syncthreads();
    }

    float inv = 1.0f / l_run;
#pragma unroll
    for (int r = 0; r < 16; r++) {
        int d0 = (r & 3) + 8 * (r >> 2) + 4 * hi;
        obuf[w][l32][d0]      = f2bf(o0[r] * inv);
        obuf[w][l32][32 + d0] = f2bf(o1[r] * inv);
    }
    asm volatile("s_waitcnt lgkmcnt(0)" ::: "memory");
    __builtin_amdgcn_sched_barrier(0);
    int b_ = bh >> 4, h = bh & 15;
    ushort* gp = ctx + ((size_t)(b_ * 2048 + q0 + l32)) * 1024 + h * 64 + hi * 32;
#pragma unroll
    for (int c = 0; c < 4; c++)
        *(s16x8*)(gp + c * 8) = *(const s16x8*)&obuf[w][l32][hi * 32 + c * 8];
}

extern "C" void kernel_launch(void* const* d_in, const int* in_sizes, int n_in,
                              void* d_out, int out_size, void* d_ws, size_t ws_size,
                              hipStream_t stream) {
    const float* X  = (const float*)d_in[0];
    const float* Wq = (const float*)d_in[1];
    const float* bq = (const float*)d_in[2];
    const float* Wk = (const float*)d_in[3];
    const float* bk = (const float*)d_in[4];
    const float* Wv = (const float*)d_in[5];
    const float* bv = (const float*)d_in[6];
    const float* Wo = (const float*)d_in[7];
    const float* bo = (const float*)d_in[8];
    float* out = (float*)d_out;

    // ws (MiB): wtq@0(2) wtk@2(2) wtv@4(2) wto@6(2) qws@8(8) kws@16(8)
    // ctx@24(8) = 32 MiB. d_out hosts V^T bf16 @0 (8 MiB) + Xbf16 @8MiB (8 MiB):
    // both dead before the final GEMM overwrites d_out.
    char* ws = (char*)d_ws;
    ushort* wtq  = (ushort*)(ws);
    ushort* wtk  = (ushort*)(ws + ((size_t)2 << 20));
    ushort* wtv  = (ushort*)(ws + ((size_t)4 << 20));
    ushort* wto  = (ushort*)(ws + ((size_t)6 << 20));
    ushort* qws  = (ushort*)(ws + ((size_t)8 << 20));
    ushort* kws  = (ushort*)(ws + ((size_t)16 << 20));
    ushort* ctx  = (ushort*)(ws + ((size_t)24 << 20));
    ushort* vtws = (ushort*)d_out;
    ushort* xbf  = (ushort*)d_out + ((size_t)4 << 20);  // +8 MiB

    transpose_k4<<<dim3(32, 32, 4), dim3(32, 8), 0, stream>>>(Wq, Wk, Wv, Wo,
                                                              wtq, wtk, wtv, wto);
    cast_bf16<<<2048, 256, 0, stream>>>(X, xbf);

    // fused QKV projection (modes 1/2/3)
    gemm_bt<<<dim3(8, 32, 3), 256, 0, stream>>>(xbf, wtq, wtk, wtv, bq, bk, bv,
                                                qws, kws, vtws, 1);

    attn<<<dim3(512), 256, 0, stream>>>(qws, kws, vtws, ctx);

    // output projection (mode 0)
    gemm_bt<<<dim3(8, 32, 1), 256, 0, stream>>>(ctx, wto, wto, wto, bo, bo, bo,
                                                out, out, out, 0);
}